// Round 9
// baseline (101.559 us; speedup 1.0000x reference)
//
#include <hip/hip_runtime.h>
#include <hip/hip_bf16.h>

#define CC 20480      // columns of X
#define PP 2048       // P
#define NROWS 2047    // rows reduced
#define SRR 10
#define HH 1024
#define NCH 64        // row chunks (32 rows each)

typedef __attribute__((ext_vector_type(8))) short short8;
typedef __attribute__((ext_vector_type(4))) float f32x4;

// ---------------- split helper ----------------------------------------
__device__ __forceinline__ void split_bf16(float v, unsigned short& hi, unsigned short& lo) {
    __hip_bfloat16 h = __float2bfloat16(v);
    float r = v - __bfloat162float(h);
    __hip_bfloat16 l2 = __float2bfloat16(r);
    hi = *(unsigned short*)&h;
    lo = *(unsigned short*)&l2;
}

// ---------------- pre: colsum gather (blocks 0..511) + wconv -----------
__global__ __launch_bounds__(256) void pre_k(const float* __restrict__ X,
                                             const int* __restrict__ p,
                                             float* __restrict__ psum,
                                             const float* __restrict__ W2,
                                             unsigned short* __restrict__ w2h,
                                             unsigned short* __restrict__ w2l,
                                             const float* __restrict__ W3,
                                             unsigned short* __restrict__ w3h,
                                             unsigned short* __restrict__ w3l) {
    int b = blockIdx.x, t = threadIdx.x;
    if (b < 512) {
        int k = (b & 7) * 256 + t;              // 0..2047
        int chunk = b >> 3;                     // 0..63
        int r0 = chunk * 32;
        int r1 = r0 + 32; if (r1 > NROWS) r1 = NROWS;
        float s = 0.f;
        int base = SRR * k;
        for (int i = r0; i < r1; ++i) {
            int col = base - p[i]; if (col < 0) col += CC;   // p[i] in [0,64)
            s += X[(size_t)i * (size_t)(SRR * CC) + col];
        }
        psum[chunk * PP + k] = s;
        return;
    }
    int bb = b - 512;
    const float* src; unsigned short *dh, *dl;
    if (bb < 256) { src = W2; dh = w2h; dl = w2l; }
    else { src = W3; dh = w3h; dl = w3l; bb -= 256; }
    int idx = bb * 4096 + t * 16;
    #pragma unroll
    for (int q = 0; q < 4; ++q) {
        float4 v = *(const float4*)&src[idx + q * 4];
        float vv[4] = {v.x, v.y, v.z, v.w};
        ushort hi4[4], lo4[4];
        #pragma unroll
        for (int i = 0; i < 4; ++i) split_bf16(vv[i], hi4[i], lo4[i]);
        *(ushort4*)&dh[idx + q * 4] = *(ushort4*)hi4;
        *(ushort4*)&dl[idx + q * 4] = *(ushort4*)lo4;
    }
}

// ---------------- prep2: x (psum reduce) + layer1, 256 blocks ----------
__global__ __launch_bounds__(256) void prep2_k(const float* __restrict__ psum,
                                               const float* __restrict__ W1,
                                               const float* __restrict__ b1,
                                               unsigned short* __restrict__ h1h,
                                               unsigned short* __restrict__ h1l) {
    __shared__ float xv[8];
    int b = blockIdx.x, t = threadIdx.x;
    int kl = t >> 5;                  // 0..7
    int c = t & 31;
    int k = b * 8 + kl;
    float s = psum[c * PP + k] + psum[(c + 32) * PP + k];
    #pragma unroll
    for (int m2 = 1; m2 < 32; m2 <<= 1) s += __shfl_xor(s, m2, 64);
    if (c == 0) xv[kl] = s * (1.0f / (float)NROWS);
    __syncthreads();
    int o0 = (t & 63) * 16;
    float w[16], bb2[16];
    #pragma unroll
    for (int q = 0; q < 4; ++q) {
        float4 wv = *(const float4*)&W1[o0 + q * 4];
        float4 bv = *(const float4*)&b1[o0 + q * 4];
        w[q*4+0] = wv.x; w[q*4+1] = wv.y; w[q*4+2] = wv.z; w[q*4+3] = wv.w;
        bb2[q*4+0] = bv.x; bb2[q*4+1] = bv.y; bb2[q*4+2] = bv.z; bb2[q*4+3] = bv.w;
    }
    #pragma unroll
    for (int pass = 0; pass < 2; ++pass) {
        int r = (t >> 6) + 4 * pass;          // 0..7
        float x = xv[r];
        ushort hi16[16], lo16[16];
        #pragma unroll
        for (int i = 0; i < 16; ++i) {
            float v = x * w[i] + bb2[i];
            v = v > 0.f ? v : 0.f;
            split_bf16(v, hi16[i], lo16[i]);
        }
        size_t base = (size_t)(b * 8 + r) * HH + o0;
        *(short8*)&h1h[base] = *(short8*)hi16;
        *(short8*)&h1h[base + 8] = *(short8*)&hi16[8];
        *(short8*)&h1l[base] = *(short8*)lo16;
        *(short8*)&h1l[base + 8] = *(short8*)&lo16[8];
    }
}

// ---------------- async global->LDS, 16B/lane -------------------------
__device__ __forceinline__ void gload16(const unsigned short* g, unsigned short* lds) {
    __builtin_amdgcn_global_load_lds(
        (const __attribute__((address_space(1))) void*)g,
        (__attribute__((address_space(3))) void*)lds,
        16, 0, 0);
}

// ---------------- bf16x3 MFMA GEMM, 64x64 tile, 2 blocks/CU ------------
// C = relu(A @ B^T + bias). BM=BN=64 BK=32, 4 waves, grid 512 = 2 blocks
// per CU (LDS 32 KB). Counted-vmcnt pipeline as R8: STAGE(next) [4 gload
// per wave] -> vmcnt(4) -> s_barrier -> ds_reads -> lgkmcnt(0) -> 12 MFMA
// (setprio) -> s_barrier. Second block's waves fill this block's bubbles.
#define BM 64
#define BN 64
#define BK 32
#define NBY 16        // N / BN
#define BUFE 8192     // ushorts per buffer (16 KB)

template<int OUT>
__global__ __launch_bounds__(256, 2) void gemm3x_k(
    const unsigned short* __restrict__ Ah, const unsigned short* __restrict__ Al,
    const unsigned short* __restrict__ Bh, const unsigned short* __restrict__ Bl,
    const float* __restrict__ bias,
    unsigned short* __restrict__ Ch, unsigned short* __restrict__ Cl,
    const float* __restrict__ W4, float* __restrict__ partial,
    int M, int N, int K)
{
    __shared__ unsigned short lds[2][BUFE];   // 32 KB -> 2 blocks/CU
    // per buffer: A_h [0,2048) 4 subtiles of 512; A_l [2048,4096);
    //             B_h [4096,6144); B_l [6144,8192)
    int lin = blockIdx.x;
    int v = (lin & 7) * (gridDim.x >> 3) + (lin >> 3);   // XCD-chunked, bijective
    int bx = v >> 4, by = v & (NBY - 1);                 // N-tile fastest
    int bm = bx * BM, bn = by * BN;
    int t = threadIdx.x, w = t >> 6, l = t & 63;
    int lr = l & 15, lk = l >> 4;
    int wr = w >> 1, wc = w & 1;

    size_t offA = (size_t)(bm + w * 16 + lr) * K + lk * 8;
    size_t offB = (size_t)(bn + w * 16 + lr) * K + lk * 8;

#define STAGE(buf, k0)                                   \
    do {                                                 \
        unsigned short* L = lds[buf];                    \
        gload16(Ah + offA + (k0), L + w * 512);          \
        gload16(Al + offA + (k0), L + 2048 + w * 512);   \
        gload16(Bh + offB + (k0), L + 4096 + w * 512);   \
        gload16(Bl + offB + (k0), L + 6144 + w * 512);   \
    } while (0)

    f32x4 acc[2][2];
    #pragma unroll
    for (int i = 0; i < 2; ++i)
        #pragma unroll
        for (int j = 0; j < 2; ++j) acc[i][j] = (f32x4)(0.f);

    STAGE(0, 0);

    int nt = K / BK;                       // 32 steps
    for (int tt = 0; tt < nt; ++tt) {
        int cur = tt & 1;
        if (tt + 1 < nt) {
            STAGE(cur ^ 1, (tt + 1) * BK);                 // 4 new loads/wave
            asm volatile("s_waitcnt vmcnt(4)" ::: "memory"); // cur's landed
        } else {
            asm volatile("s_waitcnt vmcnt(0)" ::: "memory");
        }
        __builtin_amdgcn_s_barrier();      // all waves' cur-loads landed
        __builtin_amdgcn_sched_barrier(0);
        unsigned short* L = lds[cur];
        short8 ah2[2], al2[2], bh2[2], bl2[2];
        #pragma unroll
        for (int mi = 0; mi < 2; ++mi) {
            ah2[mi] = *(const short8*)&L[(wr * 2 + mi) * 512 + l * 8];
            al2[mi] = *(const short8*)&L[2048 + (wr * 2 + mi) * 512 + l * 8];
        }
        #pragma unroll
        for (int ni = 0; ni < 2; ++ni) {
            bh2[ni] = *(const short8*)&L[4096 + (wc * 2 + ni) * 512 + l * 8];
            bl2[ni] = *(const short8*)&L[6144 + (wc * 2 + ni) * 512 + l * 8];
        }
        asm volatile("s_waitcnt lgkmcnt(0)" ::: "memory");
        __builtin_amdgcn_sched_barrier(0);                 // rule 18
        __builtin_amdgcn_s_setprio(1);
        #pragma unroll
        for (int mi = 0; mi < 2; ++mi)
            #pragma unroll
            for (int ni = 0; ni < 2; ++ni) {
                acc[mi][ni] = __builtin_amdgcn_mfma_f32_16x16x32_bf16(ah2[mi], bh2[ni], acc[mi][ni], 0, 0, 0);
                acc[mi][ni] = __builtin_amdgcn_mfma_f32_16x16x32_bf16(ah2[mi], bl2[ni], acc[mi][ni], 0, 0, 0);
                acc[mi][ni] = __builtin_amdgcn_mfma_f32_16x16x32_bf16(al2[mi], bh2[ni], acc[mi][ni], 0, 0, 0);
            }
        __builtin_amdgcn_s_setprio(0);
        __builtin_amdgcn_s_barrier();      // reads of cur done -> safe to overwrite
        __builtin_amdgcn_sched_barrier(0);
    }
#undef STAGE

    float bv[2];
    #pragma unroll
    for (int ni = 0; ni < 2; ++ni) bv[ni] = bias[bn + wc * 32 + ni * 16 + lr];
    if (OUT == 1) {
        #pragma unroll
        for (int mi = 0; mi < 2; ++mi)
            #pragma unroll
            for (int ni = 0; ni < 2; ++ni)
                #pragma unroll
                for (int r = 0; r < 4; ++r) {
                    int row = bm + wr * 32 + mi * 16 + lk * 4 + r;
                    int col = bn + wc * 32 + ni * 16 + lr;
                    float vv = acc[mi][ni][r] + bv[ni];
                    vv = vv > 0.f ? vv : 0.f;
                    unsigned short hi, lo;
                    split_bf16(vv, hi, lo);
                    Ch[(size_t)row * N + col] = hi;
                    Cl[(size_t)row * N + col] = lo;
                }
    } else {
        float w4v[2];
        #pragma unroll
        for (int ni = 0; ni < 2; ++ni) w4v[ni] = W4[bn + wc * 32 + ni * 16 + lr];
        #pragma unroll
        for (int mi = 0; mi < 2; ++mi) {
            float ps[4];
            #pragma unroll
            for (int r = 0; r < 4; ++r) {
                float acc_d = 0.f;
                #pragma unroll
                for (int ni = 0; ni < 2; ++ni) {
                    float vv = acc[mi][ni][r] + bv[ni];
                    vv = vv > 0.f ? vv : 0.f;
                    acc_d += vv * w4v[ni];
                }
                ps[r] = acc_d;
            }
            #pragma unroll
            for (int r = 0; r < 4; ++r) {
                #pragma unroll
                for (int m2 = 1; m2 < 16; m2 <<= 1) ps[r] += __shfl_xor(ps[r], m2, 64);
            }
            if (lr == 0) {
                #pragma unroll
                for (int r = 0; r < 4; ++r) {
                    int row = bm + wr * 32 + mi * 16 + lk * 4 + r;
                    partial[(size_t)row * 32 + by * 2 + wc] = ps[r];
                }
            }
        }
    }
}

// ---------------- ysum: y[r] = sum(partial[r][:]) + b4 ----------------
__global__ __launch_bounds__(256) void ysum_k(const float* __restrict__ partial,
                                              const float* __restrict__ b4,
                                              float* __restrict__ y) {
    int r = blockIdx.x * 256 + threadIdx.x;
    float s = 0.f;
    #pragma unroll
    for (int q = 0; q < 8; ++q) {
        float4 v = *(const float4*)&partial[(size_t)r * 32 + q * 4];
        s += v.x + v.y + v.z + v.w;
    }
    y[r] = s + b4[0];
}

extern "C" void kernel_launch(void* const* d_in, const int* in_sizes, int n_in,
                              void* d_out, int out_size, void* d_ws, size_t ws_size,
                              hipStream_t stream) {
    const float* X  = (const float*)d_in[0];
    const int*   p  = (const int*)d_in[1];
    const float* W1 = (const float*)d_in[2];
    const float* b1 = (const float*)d_in[3];
    const float* W2 = (const float*)d_in[4];
    const float* b2 = (const float*)d_in[5];
    const float* W3 = (const float*)d_in[6];
    const float* b3 = (const float*)d_in[7];
    const float* W4 = (const float*)d_in[8];
    const float* b4 = (const float*)d_in[9];
    float* out = (float*)d_out;

    char* ws = (char*)d_ws;
    size_t off = 0;
    float* psum = (float*)(ws + off); off += (size_t)NCH * PP * 4;
    unsigned short* h1h = (unsigned short*)(ws + off); off += (size_t)PP * HH * 2;
    unsigned short* h1l = (unsigned short*)(ws + off); off += (size_t)PP * HH * 2;
    unsigned short* h2h = (unsigned short*)(ws + off); off += (size_t)PP * HH * 2;
    unsigned short* h2l = (unsigned short*)(ws + off); off += (size_t)PP * HH * 2;
    unsigned short* w2h = (unsigned short*)(ws + off); off += (size_t)HH * HH * 2;
    unsigned short* w2l = (unsigned short*)(ws + off); off += (size_t)HH * HH * 2;
    unsigned short* w3h = (unsigned short*)(ws + off); off += (size_t)HH * HH * 2;
    unsigned short* w3l = (unsigned short*)(ws + off); off += (size_t)HH * HH * 2;
    float* partial = (float*)(ws + off); off += (size_t)PP * 32 * 4;

    pre_k<<<1024, 256, 0, stream>>>(X, p, psum, W2, w2h, w2l, W3, w3h, w3l);
    prep2_k<<<256, 256, 0, stream>>>(psum, W1, b1, h1h, h1l);
    gemm3x_k<1><<<(PP / BM) * (HH / BN), 256, 0, stream>>>(
        h1h, h1l, w2h, w2l, b2, h2h, h2l, (const float*)nullptr, (float*)nullptr, PP, HH, HH);
    gemm3x_k<2><<<(PP / BM) * (HH / BN), 256, 0, stream>>>(
        h2h, h2l, w3h, w3l, b3, (unsigned short*)nullptr, (unsigned short*)nullptr, W4, partial, PP, HH, HH);
    ysum_k<<<PP / 256, 256, 0, stream>>>(partial, b4, out);
}

// Round 10
// 89.051 us; speedup vs baseline: 1.1405x; 1.1405x over previous
//
#include <hip/hip_runtime.h>
#include <hip/hip_bf16.h>

#define CC 20480      // columns of X
#define PP 2048       // P
#define NROWS 2047    // rows reduced
#define SRR 10
#define HH 1024
#define NCH 64        // row chunks (32 rows each)

typedef __attribute__((ext_vector_type(8))) short short8;
typedef __attribute__((ext_vector_type(4))) float f32x4;

// ---------------- split helper ----------------------------------------
__device__ __forceinline__ void split_bf16(float v, unsigned short& hi, unsigned short& lo) {
    __hip_bfloat16 h = __float2bfloat16(v);
    float r = v - __bfloat162float(h);
    __hip_bfloat16 l2 = __float2bfloat16(r);
    hi = *(unsigned short*)&h;
    lo = *(unsigned short*)&l2;
}

// ---------------- colsum: strided gather (proven R6 form) --------------
__global__ __launch_bounds__(256) void colsum_k(const float* __restrict__ X,
                                                const int* __restrict__ p,
                                                float* __restrict__ psum) {
    int b = blockIdx.x, t = threadIdx.x;
    int k = (b & 7) * 256 + t;              // 0..2047
    int chunk = b >> 3;                     // 0..63
    int r0 = chunk * 32;
    int r1 = r0 + 32; if (r1 > NROWS) r1 = NROWS;
    float s = 0.f;
    int base = SRR * k;
    for (int i = r0; i < r1; ++i) {
        int col = base - p[i]; if (col < 0) col += CC;   // p[i] in [0,64)
        s += X[(size_t)i * (size_t)(SRR * CC) + col];
    }
    psum[chunk * PP + k] = s;
}

// ---------------- async global->LDS, 16B/lane -------------------------
__device__ __forceinline__ void gload16(const unsigned short* g, unsigned short* lds) {
    __builtin_amdgcn_global_load_lds(
        (const __attribute__((address_space(1))) void*)g,
        (__attribute__((address_space(3))) void*)lds,
        16, 0, 0);
}

#define BM 128
#define BN 64
#define BK 32

// ======================================================================
// GEMM1: h2 = relu(h1 @ W2^T + b2), h1 generated ON THE FLY from
// x (psum-reduce in prologue), W1, b1. B = W2 fp32, reg-staged + split.
// 8 waves, grid 256 = 1 block/CU, counted pipeline (no gload_lds here;
// compiler tracks reg-load deps; only lgkm/barrier discipline manual).
// ======================================================================
__global__ __launch_bounds__(512, 2) void gemm1_k(
    const float* __restrict__ psum,
    const float* __restrict__ W1, const float* __restrict__ b1,
    const float* __restrict__ W2, const float* __restrict__ b2,
    unsigned short* __restrict__ Ch, unsigned short* __restrict__ Cl)
{
    __shared__ unsigned short Bb[2][4096];   // per buf: hi [0,2048), lo [2048,4096)
    __shared__ float w1f[1024], b1f[1024], xv[128];

    int lin = blockIdx.x;
    int v = (lin & 7) * 32 + (lin >> 3);     // XCD-chunked, grid=256
    int bx = v >> 4, by = v & 15;
    int bm = bx * BM, bn = by * BN;
    int t = threadIdx.x, w = t >> 6, l = t & 63;
    int lr = l & 15, lk = l >> 4;
    int wr = w >> 1, wc = w & 1;

    // ---- prologue: xv, W1/b1 to LDS ----
    {
        int row = t >> 2, q = t & 3;
        float s = 0.f;
        #pragma unroll
        for (int j = 0; j < 16; ++j) s += psum[(q * 16 + j) * PP + bm + row];
        s += __shfl_xor(s, 1, 64);
        s += __shfl_xor(s, 2, 64);
        if (q == 0) xv[row] = s * (1.0f / (float)NROWS);
        if (t < 256) *(float4*)&w1f[t * 4] = *(const float4*)&W1[t * 4];
        else *(float4*)&b1f[(t - 256) * 4] = *(const float4*)&b1[(t - 256) * 4];
    }

    // ---- B reg-stage setup (W2 fp32 -> split -> LDS) ----
    int rowB = w * 8 + (l >> 3);             // 0..63
    int e = l & 7;
    int waddr = (rowB >> 4) * 512 + (rowB & 15) * 8 + (e >> 1) * 128 + 4 * (e & 1);
    const float* gB = W2 + (size_t)(bn + rowB) * HH + e * 4;

#define BSPLIT(buf, rb)                                              \
    do {                                                             \
        ushort h4[4], l4[4];                                         \
        split_bf16((rb).x, h4[0], l4[0]);                            \
        split_bf16((rb).y, h4[1], l4[1]);                            \
        split_bf16((rb).z, h4[2], l4[2]);                            \
        split_bf16((rb).w, h4[3], l4[3]);                            \
        *(ushort4*)&Bb[buf][waddr] = *(ushort4*)h4;                  \
        *(ushort4*)&Bb[buf][2048 + waddr] = *(ushort4*)l4;           \
    } while (0)

    float4 rb0 = *(const float4*)(gB);           // tile 0
    float4 rb1 = *(const float4*)(gB + BK);      // tile 1
    BSPLIT(0, rb0);
    __syncthreads();                              // xv, w1f, b1f, Bb[0] ready

    float x0 = xv[wr * 32 + lr], x1 = xv[wr * 32 + 16 + lr];

    f32x4 acc[2][2];
    #pragma unroll
    for (int i = 0; i < 2; ++i)
        #pragma unroll
        for (int j = 0; j < 2; ++j) acc[i][j] = (f32x4)(0.f);

    int nt = HH / BK;                             // 32
#define G1BODY(TT, CUR, RBS, RBL)                                              \
    do {                                                                       \
        if ((TT) + 1 < nt) {                                                   \
            BSPLIT((CUR) ^ 1, RBS);                                            \
            if ((TT) + 2 < nt) RBL = *(const float4*)(gB + ((TT) + 2) * BK);   \
        }                                                                      \
        int k0 = (TT) * BK;                                                    \
        float4 wva = *(const float4*)&w1f[k0 + lk * 8];                        \
        float4 wvb = *(const float4*)&w1f[k0 + lk * 8 + 4];                    \
        float4 bva = *(const float4*)&b1f[k0 + lk * 8];                        \
        float4 bvb = *(const float4*)&b1f[k0 + lk * 8 + 4];                    \
        float wv[8] = {wva.x, wva.y, wva.z, wva.w, wvb.x, wvb.y, wvb.z, wvb.w};\
        float bv2[8] = {bva.x, bva.y, bva.z, bva.w, bvb.x, bvb.y, bvb.z, bvb.w};\
        ushort ahh[2][8], all2[2][8];                                          \
        _Pragma("unroll")                                                      \
        for (int mi = 0; mi < 2; ++mi) {                                       \
            float xm = mi ? x1 : x0;                                           \
            _Pragma("unroll")                                                  \
            for (int j = 0; j < 8; ++j) {                                      \
                float h = fmaf(xm, wv[j], bv2[j]);                             \
                h = h > 0.f ? h : 0.f;                                         \
                split_bf16(h, ahh[mi][j], all2[mi][j]);                        \
            }                                                                  \
        }                                                                      \
        short8 bh2[2], bl2[2];                                                 \
        _Pragma("unroll")                                                      \
        for (int ni = 0; ni < 2; ++ni) {                                       \
            bh2[ni] = *(const short8*)&Bb[CUR][(wc * 2 + ni) * 512 + l * 8];   \
            bl2[ni] = *(const short8*)&Bb[CUR][2048 + (wc * 2 + ni) * 512 + l * 8];\
        }                                                                      \
        asm volatile("s_waitcnt lgkmcnt(0)" ::: "memory");                     \
        __builtin_amdgcn_sched_barrier(0);                                     \
        __builtin_amdgcn_s_setprio(1);                                         \
        _Pragma("unroll")                                                      \
        for (int mi = 0; mi < 2; ++mi) {                                       \
            short8 ah2 = *(short8*)ahh[mi];                                    \
            short8 al2 = *(short8*)all2[mi];                                   \
            _Pragma("unroll")                                                  \
            for (int ni = 0; ni < 2; ++ni) {                                   \
                acc[mi][ni] = __builtin_amdgcn_mfma_f32_16x16x32_bf16(ah2, bh2[ni], acc[mi][ni], 0, 0, 0); \
                acc[mi][ni] = __builtin_amdgcn_mfma_f32_16x16x32_bf16(ah2, bl2[ni], acc[mi][ni], 0, 0, 0); \
                acc[mi][ni] = __builtin_amdgcn_mfma_f32_16x16x32_bf16(al2, bh2[ni], acc[mi][ni], 0, 0, 0); \
            }                                                                  \
        }                                                                      \
        __builtin_amdgcn_s_setprio(0);                                         \
        __builtin_amdgcn_s_barrier();                                          \
        __builtin_amdgcn_sched_barrier(0);                                     \
    } while (0)

    for (int tt = 0; tt < nt; tt += 2) {
        G1BODY(tt,     0, rb1, rb0);
        G1BODY(tt + 1, 1, rb0, rb1);
    }
#undef G1BODY

    // epilogue: write h2 split. C/D layout col=l&15, row=(l>>4)*4+r
    float bv[2];
    #pragma unroll
    for (int ni = 0; ni < 2; ++ni) bv[ni] = b2[bn + wc * 32 + ni * 16 + lr];
    #pragma unroll
    for (int mi = 0; mi < 2; ++mi)
        #pragma unroll
        for (int ni = 0; ni < 2; ++ni)
            #pragma unroll
            for (int r = 0; r < 4; ++r) {
                int row = bm + wr * 32 + mi * 16 + lk * 4 + r;
                int col = bn + wc * 32 + ni * 16 + lr;
                float vv = acc[mi][ni][r] + bv[ni];
                vv = vv > 0.f ? vv : 0.f;
                unsigned short hi, lo;
                split_bf16(vv, hi, lo);
                Ch[(size_t)row * HH + col] = hi;
                Cl[(size_t)row * HH + col] = lo;
            }
}

// ======================================================================
// GEMM2: partial[row] = relu(h2 @ W3^T + b3) . W4  (fused layer-4 dots)
// A = h2 hi/lo via global_load_lds (R8 layout); B = W3 fp32 reg-staged.
// ======================================================================
__global__ __launch_bounds__(512, 2) void gemm2_k(
    const unsigned short* __restrict__ Ah, const unsigned short* __restrict__ Al,
    const float* __restrict__ W3, const float* __restrict__ b3,
    const float* __restrict__ W4, float* __restrict__ partial)
{
    __shared__ unsigned short Ab[2][8192];   // per buf: hi [0,4096), lo [4096,8192)
    __shared__ unsigned short Bb[2][4096];

    int lin = blockIdx.x;
    int v = (lin & 7) * 32 + (lin >> 3);
    int bx = v >> 4, by = v & 15;
    int bm = bx * BM, bn = by * BN;
    int t = threadIdx.x, w = t >> 6, l = t & 63;
    int lr = l & 15, lk = l >> 4;
    int wr = w >> 1, wc = w & 1;

    size_t offA = (size_t)(bm + w * 16 + lr) * HH + lk * 8;

#define ASTAGE(buf, k0)                                          \
    do {                                                         \
        gload16(Ah + offA + (k0), Ab[buf] + w * 512);            \
        gload16(Al + offA + (k0), Ab[buf] + 4096 + w * 512);     \
    } while (0)

    int rowB = w * 8 + (l >> 3);
    int e = l & 7;
    int waddr = (rowB >> 4) * 512 + (rowB & 15) * 8 + (e >> 1) * 128 + 4 * (e & 1);
    const float* gB = W3 + (size_t)(bn + rowB) * HH + e * 4;

    ASTAGE(0, 0);
    float4 rb0 = *(const float4*)(gB);
    float4 rb1 = *(const float4*)(gB + BK);
    BSPLIT(0, rb0);
    __syncthreads();

    f32x4 acc[2][2];
    #pragma unroll
    for (int i = 0; i < 2; ++i)
        #pragma unroll
        for (int j = 0; j < 2; ++j) acc[i][j] = (f32x4)(0.f);

    int nt = HH / BK;
#define G2BODY(TT, CUR, RBS, RBL)                                              \
    do {                                                                       \
        if ((TT) + 1 < nt) {                                                   \
            ASTAGE((CUR) ^ 1, ((TT) + 1) * BK);                                \
            BSPLIT((CUR) ^ 1, RBS);                                            \
            if ((TT) + 2 < nt) RBL = *(const float4*)(gB + ((TT) + 2) * BK);   \
        }                                                                      \
        short8 ah2[2], al2[2], bh2[2], bl2[2];                                 \
        _Pragma("unroll")                                                      \
        for (int mi = 0; mi < 2; ++mi) {                                       \
            ah2[mi] = *(const short8*)&Ab[CUR][(wr * 2 + mi) * 512 + l * 8];   \
            al2[mi] = *(const short8*)&Ab[CUR][4096 + (wr * 2 + mi) * 512 + l * 8];\
        }                                                                      \
        _Pragma("unroll")                                                      \
        for (int ni = 0; ni < 2; ++ni) {                                       \
            bh2[ni] = *(const short8*)&Bb[CUR][(wc * 2 + ni) * 512 + l * 8];   \
            bl2[ni] = *(const short8*)&Bb[CUR][2048 + (wc * 2 + ni) * 512 + l * 8];\
        }                                                                      \
        asm volatile("s_waitcnt lgkmcnt(0)" ::: "memory");                     \
        __builtin_amdgcn_sched_barrier(0);                                     \
        __builtin_amdgcn_s_setprio(1);                                         \
        _Pragma("unroll")                                                      \
        for (int mi = 0; mi < 2; ++mi)                                         \
            _Pragma("unroll")                                                  \
            for (int ni = 0; ni < 2; ++ni) {                                   \
                acc[mi][ni] = __builtin_amdgcn_mfma_f32_16x16x32_bf16(ah2[mi], bh2[ni], acc[mi][ni], 0, 0, 0); \
                acc[mi][ni] = __builtin_amdgcn_mfma_f32_16x16x32_bf16(ah2[mi], bl2[ni], acc[mi][ni], 0, 0, 0); \
                acc[mi][ni] = __builtin_amdgcn_mfma_f32_16x16x32_bf16(al2[mi], bh2[ni], acc[mi][ni], 0, 0, 0); \
            }                                                                  \
        __builtin_amdgcn_s_setprio(0);                                         \
        if ((TT) + 1 < nt) asm volatile("s_waitcnt vmcnt(1)" ::: "memory");    \
        else               asm volatile("s_waitcnt vmcnt(0)" ::: "memory");    \
        __builtin_amdgcn_s_barrier();                                          \
        __builtin_amdgcn_sched_barrier(0);                                     \
    } while (0)

    for (int tt = 0; tt < nt; tt += 2) {
        G2BODY(tt,     0, rb1, rb0);
        G2BODY(tt + 1, 1, rb0, rb1);
    }
#undef G2BODY
#undef BSPLIT

    // epilogue: fused W4 partial dots
    float bv[2], w4v[2];
    #pragma unroll
    for (int ni = 0; ni < 2; ++ni) {
        bv[ni]  = b3[bn + wc * 32 + ni * 16 + lr];
        w4v[ni] = W4[bn + wc * 32 + ni * 16 + lr];
    }
    #pragma unroll
    for (int mi = 0; mi < 2; ++mi) {
        float ps[4];
        #pragma unroll
        for (int r = 0; r < 4; ++r) {
            float acc_d = 0.f;
            #pragma unroll
            for (int ni = 0; ni < 2; ++ni) {
                float vv = acc[mi][ni][r] + bv[ni];
                vv = vv > 0.f ? vv : 0.f;
                acc_d += vv * w4v[ni];
            }
            ps[r] = acc_d;
        }
        #pragma unroll
        for (int r = 0; r < 4; ++r) {
            #pragma unroll
            for (int m2 = 1; m2 < 16; m2 <<= 1) ps[r] += __shfl_xor(ps[r], m2, 64);
        }
        if (lr == 0) {
            #pragma unroll
            for (int r = 0; r < 4; ++r) {
                int row = bm + wr * 32 + mi * 16 + lk * 4 + r;
                partial[(size_t)row * 32 + by * 2 + wc] = ps[r];
            }
        }
    }
}

// ---------------- ysum: y[r] = sum(partial[r][:]) + b4 ----------------
__global__ __launch_bounds__(256) void ysum_k(const float* __restrict__ partial,
                                              const float* __restrict__ b4,
                                              float* __restrict__ y) {
    int r = blockIdx.x * 256 + threadIdx.x;
    float s = 0.f;
    #pragma unroll
    for (int q = 0; q < 8; ++q) {
        float4 v = *(const float4*)&partial[(size_t)r * 32 + q * 4];
        s += v.x + v.y + v.z + v.w;
    }
    y[r] = s + b4[0];
}

extern "C" void kernel_launch(void* const* d_in, const int* in_sizes, int n_in,
                              void* d_out, int out_size, void* d_ws, size_t ws_size,
                              hipStream_t stream) {
    const float* X  = (const float*)d_in[0];
    const int*   p  = (const int*)d_in[1];
    const float* W1 = (const float*)d_in[2];
    const float* b1 = (const float*)d_in[3];
    const float* W2 = (const float*)d_in[4];
    const float* b2 = (const float*)d_in[5];
    const float* W3 = (const float*)d_in[6];
    const float* b3 = (const float*)d_in[7];
    const float* W4 = (const float*)d_in[8];
    const float* b4 = (const float*)d_in[9];
    float* out = (float*)d_out;

    char* ws = (char*)d_ws;
    size_t off = 0;
    float* psum = (float*)(ws + off); off += (size_t)NCH * PP * 4;
    unsigned short* h2h = (unsigned short*)(ws + off); off += (size_t)PP * HH * 2;
    unsigned short* h2l = (unsigned short*)(ws + off); off += (size_t)PP * HH * 2;
    float* partial = (float*)(ws + off); off += (size_t)PP * 32 * 4;

    colsum_k<<<512, 256, 0, stream>>>(X, p, psum);
    gemm1_k<<<256, 512, 0, stream>>>(psum, W1, b1, W2, b2, h2h, h2l);
    gemm2_k<<<256, 512, 0, stream>>>(h2h, h2l, W3, b3, W4, partial);
    ysum_k<<<PP / 256, 256, 0, stream>>>(partial, b4, out);
}

// Round 11
// 83.974 us; speedup vs baseline: 1.2094x; 1.0605x over previous
//
#include <hip/hip_runtime.h>
#include <hip/hip_bf16.h>

#define CC 20480      // columns of X
#define PP 2048       // P
#define NROWS 2047    // rows reduced
#define SRR 10
#define HH 1024
#define NCH 64        // row chunks (32 rows each)

typedef __attribute__((ext_vector_type(8))) short short8;
typedef __attribute__((ext_vector_type(4))) float f32x4;

// ---------------- split helper ----------------------------------------
__device__ __forceinline__ void split_bf16(float v, unsigned short& hi, unsigned short& lo) {
    __hip_bfloat16 h = __float2bfloat16(v);
    float r = v - __bfloat162float(h);
    __hip_bfloat16 l2 = __float2bfloat16(r);
    hi = *(unsigned short*)&h;
    lo = *(unsigned short*)&l2;
}

// ---------------- pre: colsum gather (blocks 0..511) + wconv -----------
__global__ __launch_bounds__(256) void pre_k(const float* __restrict__ X,
                                             const int* __restrict__ p,
                                             float* __restrict__ psum,
                                             const float* __restrict__ W2,
                                             unsigned short* __restrict__ w2h,
                                             unsigned short* __restrict__ w2l,
                                             const float* __restrict__ W3,
                                             unsigned short* __restrict__ w3h,
                                             unsigned short* __restrict__ w3l) {
    int b = blockIdx.x, t = threadIdx.x;
    if (b < 512) {
        int k = (b & 7) * 256 + t;              // 0..2047
        int chunk = b >> 3;                     // 0..63
        int r0 = chunk * 32;
        int r1 = r0 + 32; if (r1 > NROWS) r1 = NROWS;
        float s = 0.f;
        int base = SRR * k;
        for (int i = r0; i < r1; ++i) {
            int col = base - p[i]; if (col < 0) col += CC;   // p[i] in [0,64)
            s += X[(size_t)i * (size_t)(SRR * CC) + col];
        }
        psum[chunk * PP + k] = s;
        return;
    }
    int bb = b - 512;
    const float* src; unsigned short *dh, *dl;
    if (bb < 256) { src = W2; dh = w2h; dl = w2l; }
    else { src = W3; dh = w3h; dl = w3l; bb -= 256; }
    int idx = bb * 4096 + t * 16;
    #pragma unroll
    for (int q = 0; q < 4; ++q) {
        float4 v = *(const float4*)&src[idx + q * 4];
        float vv[4] = {v.x, v.y, v.z, v.w};
        ushort hi4[4], lo4[4];
        #pragma unroll
        for (int i = 0; i < 4; ++i) split_bf16(vv[i], hi4[i], lo4[i]);
        *(ushort4*)&dh[idx + q * 4] = *(ushort4*)hi4;
        *(ushort4*)&dl[idx + q * 4] = *(ushort4*)lo4;
    }
}

// ---------------- async global->LDS, 16B/lane -------------------------
__device__ __forceinline__ void gload16(const unsigned short* g, unsigned short* lds) {
    __builtin_amdgcn_global_load_lds(
        (const __attribute__((address_space(1))) void*)g,
        (__attribute__((address_space(3))) void*)lds,
        16, 0, 0);
}

#define BM 128
#define BN 64
#define BK 32

// ======================================================================
// GEMM1: h2 = relu(h1 @ W2^T + b2), h1 = relu(x*W1+b1) generated on the
// fly (x from psum prologue; W1/b1 in LDS, broadcast reads). B = pre-split
// w2h/w2l via global_load_lds (1 load/wave/step, counted vmcnt(1)).
// No lgkm pin before MFMAs: compiler emits fine-grained lgkmcnt.
// ======================================================================
__global__ __launch_bounds__(512, 2) void gemm1_k(
    const float* __restrict__ psum,
    const float* __restrict__ W1, const float* __restrict__ b1,
    const unsigned short* __restrict__ Bh, const unsigned short* __restrict__ Bl,
    const float* __restrict__ b2,
    unsigned short* __restrict__ Ch, unsigned short* __restrict__ Cl)
{
    __shared__ unsigned short Bb[2][4096];   // per buf: hi [0,2048), lo [2048,4096)
    __shared__ float w1f[1024], b1f[1024], xv[128];

    int lin = blockIdx.x;
    int v = (lin & 7) * 32 + (lin >> 3);     // XCD-chunked, grid=256
    int bx = v >> 4, by = v & 15;
    int bm = bx * BM, bn = by * BN;
    int t = threadIdx.x, w = t >> 6, l = t & 63;
    int lr = l & 15, lk = l >> 4;
    int wr = w >> 1, wc = w & 1;

    size_t offB = (size_t)(bn + (w & 3) * 16 + lr) * HH + lk * 8;
#define BSTAGE(buf, k0)                                                      \
    do {                                                                     \
        if (w < 4) gload16(Bh + offB + (k0), Bb[buf] + w * 512);             \
        else       gload16(Bl + offB + (k0), Bb[buf] + 2048 + (w - 4) * 512);\
    } while (0)

    BSTAGE(0, 0);
    // ---- prologue: xv, W1/b1 to LDS ----
    {
        int row = t >> 2, q = t & 3;
        float s = 0.f;
        #pragma unroll
        for (int j = 0; j < 16; ++j) s += psum[(q * 16 + j) * PP + bm + row];
        s += __shfl_xor(s, 1, 64);
        s += __shfl_xor(s, 2, 64);
        if (q == 0) xv[row] = s * (1.0f / (float)NROWS);
        if (t < 256) *(float4*)&w1f[t * 4] = *(const float4*)&W1[t * 4];
        else *(float4*)&b1f[(t - 256) * 4] = *(const float4*)&b1[(t - 256) * 4];
    }
    __syncthreads();                         // xv/w1f/b1f + Bb[0] ready

    float x0 = xv[wr * 32 + lr], x1 = xv[wr * 32 + 16 + lr];

    f32x4 acc[2][2];
    #pragma unroll
    for (int i = 0; i < 2; ++i)
        #pragma unroll
        for (int j = 0; j < 2; ++j) acc[i][j] = (f32x4)(0.f);

    int nt = HH / BK;                        // 32
    for (int tt = 0; tt < nt; ++tt) {
        int cur = tt & 1;
        if (tt + 1 < nt) {
            BSTAGE(cur ^ 1, (tt + 1) * BK);
            asm volatile("s_waitcnt vmcnt(1)" ::: "memory");
        } else {
            asm volatile("s_waitcnt vmcnt(0)" ::: "memory");
        }
        __builtin_amdgcn_s_barrier();
        __builtin_amdgcn_sched_barrier(0);
        __builtin_amdgcn_s_setprio(1);
        int k0 = tt * BK;
        // A on the fly: 16 h-values per lane (rows wr*32+{lr,16+lr}, k slice)
        float4 wva = *(const float4*)&w1f[k0 + lk * 8];
        float4 wvb = *(const float4*)&w1f[k0 + lk * 8 + 4];
        float4 bva = *(const float4*)&b1f[k0 + lk * 8];
        float4 bvb = *(const float4*)&b1f[k0 + lk * 8 + 4];
        float wv[8] = {wva.x, wva.y, wva.z, wva.w, wvb.x, wvb.y, wvb.z, wvb.w};
        float bv2[8] = {bva.x, bva.y, bva.z, bva.w, bvb.x, bvb.y, bvb.z, bvb.w};
        ushort ahh[2][8], all2[2][8];
        #pragma unroll
        for (int mi = 0; mi < 2; ++mi) {
            float xm = mi ? x1 : x0;
            #pragma unroll
            for (int j = 0; j < 8; ++j) {
                float h = fmaf(xm, wv[j], bv2[j]);
                h = h > 0.f ? h : 0.f;
                split_bf16(h, ahh[mi][j], all2[mi][j]);
            }
        }
        short8 bh2[2], bl2[2];
        #pragma unroll
        for (int ni = 0; ni < 2; ++ni) {
            bh2[ni] = *(const short8*)&Bb[cur][(wc * 2 + ni) * 512 + l * 8];
            bl2[ni] = *(const short8*)&Bb[cur][2048 + (wc * 2 + ni) * 512 + l * 8];
        }
        #pragma unroll
        for (int mi = 0; mi < 2; ++mi) {
            short8 ah2 = *(short8*)ahh[mi];
            short8 al2 = *(short8*)all2[mi];
            #pragma unroll
            for (int ni = 0; ni < 2; ++ni) {
                acc[mi][ni] = __builtin_amdgcn_mfma_f32_16x16x32_bf16(ah2, bh2[ni], acc[mi][ni], 0, 0, 0);
                acc[mi][ni] = __builtin_amdgcn_mfma_f32_16x16x32_bf16(ah2, bl2[ni], acc[mi][ni], 0, 0, 0);
                acc[mi][ni] = __builtin_amdgcn_mfma_f32_16x16x32_bf16(al2, bh2[ni], acc[mi][ni], 0, 0, 0);
            }
        }
        __builtin_amdgcn_s_setprio(0);
        __builtin_amdgcn_sched_barrier(0);
        __builtin_amdgcn_s_barrier();
        __builtin_amdgcn_sched_barrier(0);
    }
#undef BSTAGE

    // epilogue: write h2 split. C/D layout col=l&15, row=(l>>4)*4+r
    float bv[2];
    #pragma unroll
    for (int ni = 0; ni < 2; ++ni) bv[ni] = b2[bn + wc * 32 + ni * 16 + lr];
    #pragma unroll
    for (int mi = 0; mi < 2; ++mi)
        #pragma unroll
        for (int ni = 0; ni < 2; ++ni)
            #pragma unroll
            for (int r = 0; r < 4; ++r) {
                int row = bm + wr * 32 + mi * 16 + lk * 4 + r;
                int col = bn + wc * 32 + ni * 16 + lr;
                float vv = acc[mi][ni][r] + bv[ni];
                vv = vv > 0.f ? vv : 0.f;
                unsigned short hi, lo;
                split_bf16(vv, hi, lo);
                Ch[(size_t)row * HH + col] = hi;
                Cl[(size_t)row * HH + col] = lo;
            }
}

// ======================================================================
// GEMM2: partial = (relu(h2 @ W3^T + b3)) . W4 fused. A,B both via
// global_load_lds (3 loads/wave, counted vmcnt(3)). No lgkm pin.
// ======================================================================
__global__ __launch_bounds__(512, 2) void gemm2_k(
    const unsigned short* __restrict__ Ah, const unsigned short* __restrict__ Al,
    const unsigned short* __restrict__ Bh, const unsigned short* __restrict__ Bl,
    const float* __restrict__ b3,
    const float* __restrict__ W4, float* __restrict__ partial)
{
    __shared__ unsigned short lds[2][12288];   // 48 KB
    // per buffer: A_hi [0,4096) 8 subtiles of 512; A_lo [4096,8192);
    //             B_hi [8192,10240) 4 subtiles; B_lo [10240,12288)
    int lin = blockIdx.x;
    int v = (lin & 7) * 32 + (lin >> 3);
    int bx = v >> 4, by = v & 15;
    int bm = bx * BM, bn = by * BN;
    int t = threadIdx.x, w = t >> 6, l = t & 63;
    int lr = l & 15, lk = l >> 4;
    int wr = w >> 1, wc = w & 1;

    size_t offA = (size_t)(bm + w * 16 + lr) * HH + lk * 8;
    size_t offB = (size_t)(bn + (w & 3) * 16 + lr) * HH + lk * 8;

#define STAGE(buf, k0)                                                   \
    do {                                                                 \
        unsigned short* L = lds[buf];                                    \
        gload16(Ah + offA + (k0), L + w * 512);                          \
        gload16(Al + offA + (k0), L + 4096 + w * 512);                   \
        if (w < 4) gload16(Bh + offB + (k0), L + 8192 + w * 512);        \
        else       gload16(Bl + offB + (k0), L + 10240 + (w - 4) * 512); \
    } while (0)

    f32x4 acc[2][2];
    #pragma unroll
    for (int i = 0; i < 2; ++i)
        #pragma unroll
        for (int j = 0; j < 2; ++j) acc[i][j] = (f32x4)(0.f);

    STAGE(0, 0);

    int nt = HH / BK;                      // 32 steps
    for (int tt = 0; tt < nt; ++tt) {
        int cur = tt & 1;
        if (tt + 1 < nt) {
            STAGE(cur ^ 1, (tt + 1) * BK);
            asm volatile("s_waitcnt vmcnt(3)" ::: "memory");
        } else {
            asm volatile("s_waitcnt vmcnt(0)" ::: "memory");
        }
        __builtin_amdgcn_s_barrier();
        __builtin_amdgcn_sched_barrier(0);
        __builtin_amdgcn_s_setprio(1);
        unsigned short* L = lds[cur];
        short8 ah2[2], al2[2], bh2[2], bl2[2];
        #pragma unroll
        for (int mi = 0; mi < 2; ++mi) {
            ah2[mi] = *(const short8*)&L[(wr * 2 + mi) * 512 + l * 8];
            al2[mi] = *(const short8*)&L[4096 + (wr * 2 + mi) * 512 + l * 8];
        }
        #pragma unroll
        for (int ni = 0; ni < 2; ++ni) {
            bh2[ni] = *(const short8*)&L[8192 + (wc * 2 + ni) * 512 + l * 8];
            bl2[ni] = *(const short8*)&L[10240 + (wc * 2 + ni) * 512 + l * 8];
        }
        #pragma unroll
        for (int mi = 0; mi < 2; ++mi)
            #pragma unroll
            for (int ni = 0; ni < 2; ++ni) {
                acc[mi][ni] = __builtin_amdgcn_mfma_f32_16x16x32_bf16(ah2[mi], bh2[ni], acc[mi][ni], 0, 0, 0);
                acc[mi][ni] = __builtin_amdgcn_mfma_f32_16x16x32_bf16(ah2[mi], bl2[ni], acc[mi][ni], 0, 0, 0);
                acc[mi][ni] = __builtin_amdgcn_mfma_f32_16x16x32_bf16(al2[mi], bh2[ni], acc[mi][ni], 0, 0, 0);
            }
        __builtin_amdgcn_s_setprio(0);
        __builtin_amdgcn_sched_barrier(0);
        __builtin_amdgcn_s_barrier();
        __builtin_amdgcn_sched_barrier(0);
    }
#undef STAGE

    // epilogue: fused W4 partial dots
    float bv[2], w4v[2];
    #pragma unroll
    for (int ni = 0; ni < 2; ++ni) {
        bv[ni]  = b3[bn + wc * 32 + ni * 16 + lr];
        w4v[ni] = W4[bn + wc * 32 + ni * 16 + lr];
    }
    #pragma unroll
    for (int mi = 0; mi < 2; ++mi) {
        float ps[4];
        #pragma unroll
        for (int r = 0; r < 4; ++r) {
            float acc_d = 0.f;
            #pragma unroll
            for (int ni = 0; ni < 2; ++ni) {
                float vv = acc[mi][ni][r] + bv[ni];
                vv = vv > 0.f ? vv : 0.f;
                acc_d += vv * w4v[ni];
            }
            ps[r] = acc_d;
        }
        #pragma unroll
        for (int r = 0; r < 4; ++r) {
            #pragma unroll
            for (int m2 = 1; m2 < 16; m2 <<= 1) ps[r] += __shfl_xor(ps[r], m2, 64);
        }
        if (lr == 0) {
            #pragma unroll
            for (int r = 0; r < 4; ++r) {
                int row = bm + wr * 32 + mi * 16 + lk * 4 + r;
                partial[(size_t)row * 32 + by * 2 + wc] = ps[r];
            }
        }
    }
}

// ---------------- ysum: y[r] = sum(partial[r][:]) + b4 ----------------
__global__ __launch_bounds__(256) void ysum_k(const float* __restrict__ partial,
                                              const float* __restrict__ b4,
                                              float* __restrict__ y) {
    int r = blockIdx.x * 256 + threadIdx.x;
    float s = 0.f;
    #pragma unroll
    for (int q = 0; q < 8; ++q) {
        float4 v = *(const float4*)&partial[(size_t)r * 32 + q * 4];
        s += v.x + v.y + v.z + v.w;
    }
    y[r] = s + b4[0];
}

extern "C" void kernel_launch(void* const* d_in, const int* in_sizes, int n_in,
                              void* d_out, int out_size, void* d_ws, size_t ws_size,
                              hipStream_t stream) {
    const float* X  = (const float*)d_in[0];
    const int*   p  = (const int*)d_in[1];
    const float* W1 = (const float*)d_in[2];
    const float* b1 = (const float*)d_in[3];
    const float* W2 = (const float*)d_in[4];
    const float* b2 = (const float*)d_in[5];
    const float* W3 = (const float*)d_in[6];
    const float* b3 = (const float*)d_in[7];
    const float* W4 = (const float*)d_in[8];
    const float* b4 = (const float*)d_in[9];
    float* out = (float*)d_out;

    char* ws = (char*)d_ws;
    size_t off = 0;
    float* psum = (float*)(ws + off); off += (size_t)NCH * PP * 4;
    unsigned short* h2h = (unsigned short*)(ws + off); off += (size_t)PP * HH * 2;
    unsigned short* h2l = (unsigned short*)(ws + off); off += (size_t)PP * HH * 2;
    unsigned short* w2h = (unsigned short*)(ws + off); off += (size_t)HH * HH * 2;
    unsigned short* w2l = (unsigned short*)(ws + off); off += (size_t)HH * HH * 2;
    unsigned short* w3h = (unsigned short*)(ws + off); off += (size_t)HH * HH * 2;
    unsigned short* w3l = (unsigned short*)(ws + off); off += (size_t)HH * HH * 2;
    float* partial = (float*)(ws + off); off += (size_t)PP * 32 * 4;

    pre_k<<<1024, 256, 0, stream>>>(X, p, psum, W2, w2h, w2l, W3, w3h, w3l);
    gemm1_k<<<256, 512, 0, stream>>>(psum, W1, b1, w2h, w2l, b2, h2h, h2l);
    gemm2_k<<<256, 512, 0, stream>>>(h2h, h2l, w3h, w3l, b3, W4, partial);
    ysum_k<<<PP / 256, 256, 0, stream>>>(partial, b4, out);
}